// Round 1
// baseline (771.297 us; speedup 1.0000x reference)
//
#include <hip/hip_runtime.h>

// ---------------------------------------------------------------------------
// SimplicialAttentionLayer2 on MI355X (gfx950)
// N=4096 simplices, D=1024 features.
//   3x: S = (Hq @ KV^T)/32 -> softmax -> *mask -> softmax -> @ KV
//   out = tanh(concat(H1,H2,H3) @ W^T + b)
// All GEMMs in bf16 MFMA (16x16x32), softmax in fp32, S stored bf16 in-place.
// ---------------------------------------------------------------------------

typedef unsigned short u16;
typedef unsigned int u32;
typedef __attribute__((ext_vector_type(8))) short short8;
typedef __attribute__((ext_vector_type(4))) float floatx4;

#define NS 4096
#define DF 1024

__device__ __forceinline__ u16 f2b(float x) {          // fp32 -> bf16 RNE
    u32 u = __float_as_uint(x);
    u32 r = (u + 0x7fffu + ((u >> 16) & 1u)) >> 16;
    return (u16)r;
}
__device__ __forceinline__ u32 packb(float a, float b) {
    return (u32)f2b(a) | ((u32)f2b(b) << 16);
}
__device__ __forceinline__ void unpack8(uint4 u, float* v) {
    v[0] = __uint_as_float(u.x << 16); v[1] = __uint_as_float(u.x & 0xffff0000u);
    v[2] = __uint_as_float(u.y << 16); v[3] = __uint_as_float(u.y & 0xffff0000u);
    v[4] = __uint_as_float(u.z << 16); v[5] = __uint_as_float(u.z & 0xffff0000u);
    v[6] = __uint_as_float(u.w << 16); v[7] = __uint_as_float(u.w & 0xffff0000u);
}

// ---------------------------------------------------------------------------
// GEMM-NT: C[M,N] = epi(alpha * A[M,K] @ B[N,K]^T), A/B bf16 row-major.
// 128x128 block tile, BK=64, 4 waves (2x2), each wave 64x64 via 4x4 MFMAs.
// Staging: global_load_lds width 16, XOR chunk swizzle (conflict-free ds_read).
// EPI=0: bf16 store (alpha applied). EPI=1: fp32 store tanh(acc + bias[col]).
// ---------------------------------------------------------------------------
template <int EPI>
__global__ __launch_bounds__(256)
void gemm_nt(const u16* __restrict__ A, const u16* __restrict__ B,
             void* __restrict__ Cv, const float* __restrict__ bias,
             int K, int lda, int ldb, int ldc, float alpha)
{
    __shared__ u16 As[128 * 64];
    __shared__ u16 Bs[128 * 64];

    const int tid  = threadIdx.x;
    const int wave = tid >> 6;
    const int lane = tid & 63;
    const int bn = blockIdx.x, bm = blockIdx.y;
    const int wm = wave >> 1, wn = wave & 1;
    const int q = lane >> 4, r16 = lane & 15;

    floatx4 acc[4][4];
#pragma unroll
    for (int i = 0; i < 4; i++)
#pragma unroll
        for (int j = 0; j < 4; j++) acc[i][j] = (floatx4){0.f, 0.f, 0.f, 0.f};

    const u16* Abase = A + (size_t)bm * 128 * lda;
    const u16* Bbase = B + (size_t)bn * 128 * ldb;

    for (int kt = 0; kt < K; kt += 64) {
        // stage A and B tiles: LDS phys chunk c' at (row) holds logical chunk c'^(row&7)
#pragma unroll
        for (int i = 0; i < 4; i++) {
            int chunk = i * 256 + wave * 64 + lane;     // 16B chunk id
            int row   = chunk >> 3;                     // 8 chunks (128B) per row
            int clog  = (chunk & 7) ^ (row & 7);
            const u16* ga = Abase + (size_t)row * lda + kt + clog * 8;
            const u16* gb = Bbase + (size_t)row * ldb + kt + clog * 8;
            __builtin_amdgcn_global_load_lds(
                (const __attribute__((address_space(1))) void*)ga,
                (__attribute__((address_space(3))) void*)&As[(i * 256 + wave * 64) * 8],
                16, 0, 0);
            __builtin_amdgcn_global_load_lds(
                (const __attribute__((address_space(1))) void*)gb,
                (__attribute__((address_space(3))) void*)&Bs[(i * 256 + wave * 64) * 8],
                16, 0, 0);
        }
        __syncthreads();   // compiler drains vmcnt before s_barrier

#pragma unroll
        for (int kk = 0; kk < 2; kk++) {
            short8 af[4], bfv[4];
#pragma unroll
            for (int mi = 0; mi < 4; mi++) {
                int row  = wm * 64 + mi * 16 + r16;     // A: m = lane&15
                int phys = (kk * 4 + q) ^ (row & 7);    // k-chunk = kk*4 + quad
                af[mi] = *(const short8*)&As[row * 64 + phys * 8];
            }
#pragma unroll
            for (int ni = 0; ni < 4; ni++) {
                int row  = wn * 64 + ni * 16 + r16;     // B: n = lane&15
                int phys = (kk * 4 + q) ^ (row & 7);
                bfv[ni] = *(const short8*)&Bs[row * 64 + phys * 8];
            }
#pragma unroll
            for (int mi = 0; mi < 4; mi++)
#pragma unroll
                for (int ni = 0; ni < 4; ni++)
                    acc[mi][ni] = __builtin_amdgcn_mfma_f32_16x16x32_bf16(
                        af[mi], bfv[ni], acc[mi][ni], 0, 0, 0);
        }
        __syncthreads();
    }

    // epilogue: D element (row = q*4 + r, col = lane&15)  [m89-verified layout]
#pragma unroll
    for (int mi = 0; mi < 4; mi++) {
#pragma unroll
        for (int ni = 0; ni < 4; ni++) {
            floatx4 v = acc[mi][ni];
            int col  = bn * 128 + wn * 64 + ni * 16 + r16;
            int rowb = bm * 128 + wm * 64 + mi * 16 + q * 4;
            if (EPI == 0) {
                u16* C = (u16*)Cv;
#pragma unroll
                for (int r = 0; r < 4; r++)
                    C[(size_t)(rowb + r) * ldc + col] = f2b(v[r] * alpha);
            } else {
                float* C = (float*)Cv;
                float bb = bias[col];
#pragma unroll
                for (int r = 0; r < 4; r++)
                    C[(size_t)(rowb + r) * ldc + col] = tanhf(v[r] * alpha + bb);
            }
        }
    }
}

// ---------------------------------------------------------------------------
// Double softmax over one row of S (bf16, in-place), with mask multiply.
// mF: fp32 mask source row-major (mask = src != 0), or null -> use u8 mB.
// ---------------------------------------------------------------------------
__device__ __forceinline__ float blockMax(float x, volatile float* red) {
#pragma unroll
    for (int off = 32; off > 0; off >>= 1) x = fmaxf(x, __shfl_xor(x, off, 64));
    __syncthreads();
    if ((threadIdx.x & 63) == 0) red[threadIdx.x >> 6] = x;
    __syncthreads();
    return fmaxf(fmaxf(red[0], red[1]), fmaxf(red[2], red[3]));
}
__device__ __forceinline__ float blockSum(float x, volatile float* red) {
#pragma unroll
    for (int off = 32; off > 0; off >>= 1) x += __shfl_xor(x, off, 64);
    __syncthreads();
    if ((threadIdx.x & 63) == 0) red[threadIdx.x >> 6] = x;
    __syncthreads();
    return red[0] + red[1] + red[2] + red[3];
}

__global__ __launch_bounds__(256)
void dsoftmax(u16* __restrict__ S, const float* __restrict__ mF,
              const unsigned char* __restrict__ mB)
{
    __shared__ float red[4];
    const int row = blockIdx.x;
    const int t   = threadIdx.x;
    u16* Srow = S + (size_t)row * NS;

    float v[16];
    uint4 u0 = ((const uint4*)Srow)[t * 2];
    uint4 u1 = ((const uint4*)Srow)[t * 2 + 1];
    unpack8(u0, v); unpack8(u1, v + 8);

    float m = -1e30f;
#pragma unroll
    for (int j = 0; j < 16; j++) m = fmaxf(m, v[j]);
    m = blockMax(m, red);

    float s = 0.f;
#pragma unroll
    for (int j = 0; j < 16; j++) { v[j] = __expf(v[j] - m); s += v[j]; }
    s = blockSum(s, red);
    float rz = 1.0f / s;

    float v2[16];
    if (mF) {
        const float* mrow = mF + (size_t)row * NS;
#pragma unroll
        for (int k = 0; k < 4; k++) {
            float4 mv = ((const float4*)mrow)[t * 4 + k];
            v2[k * 4 + 0] = (mv.x != 0.f) ? v[k * 4 + 0] * rz : 0.f;
            v2[k * 4 + 1] = (mv.y != 0.f) ? v[k * 4 + 1] * rz : 0.f;
            v2[k * 4 + 2] = (mv.z != 0.f) ? v[k * 4 + 2] * rz : 0.f;
            v2[k * 4 + 3] = (mv.w != 0.f) ? v[k * 4 + 3] * rz : 0.f;
        }
    } else {
        const uint4* mrow = (const uint4*)(mB + (size_t)row * NS);
        uint4 mu = mrow[t];
        u32 bs[4] = {mu.x, mu.y, mu.z, mu.w};
#pragma unroll
        for (int k = 0; k < 4; k++)
#pragma unroll
            for (int j = 0; j < 4; j++)
                v2[k * 4 + j] = ((bs[k] >> (8 * j)) & 0xffu) ? v[k * 4 + j] * rz : 0.f;
    }

    // second softmax: masked entries are logit 0 (still contribute exp)
    float m2 = -1e30f;
#pragma unroll
    for (int j = 0; j < 16; j++) m2 = fmaxf(m2, v2[j]);
    m2 = blockMax(m2, red);
    float s2 = 0.f;
#pragma unroll
    for (int j = 0; j < 16; j++) { v2[j] = __expf(v2[j] - m2); s2 += v2[j]; }
    s2 = blockSum(s2, red);
    float rz2 = 1.0f / s2;

    uint4 o0, o1;
    o0.x = packb(v2[0] * rz2,  v2[1] * rz2);
    o0.y = packb(v2[2] * rz2,  v2[3] * rz2);
    o0.z = packb(v2[4] * rz2,  v2[5] * rz2);
    o0.w = packb(v2[6] * rz2,  v2[7] * rz2);
    o1.x = packb(v2[8] * rz2,  v2[9] * rz2);
    o1.y = packb(v2[10] * rz2, v2[11] * rz2);
    o1.z = packb(v2[12] * rz2, v2[13] * rz2);
    o1.w = packb(v2[14] * rz2, v2[15] * rz2);
    ((uint4*)Srow)[t * 2]     = o0;
    ((uint4*)Srow)[t * 2 + 1] = o1;
}

// ---------------------------------------------------------------------------
// fp32 [R,C] -> bf16 [R,C] and bf16 transposed [C,R]
// ---------------------------------------------------------------------------
__global__ __launch_bounds__(256)
void cvt_t(const float* __restrict__ X, u16* __restrict__ Xb, u16* __restrict__ XbT,
           int R, int C)
{
    __shared__ float tile[32][33];
    const int tx = threadIdx.x, ty = threadIdx.y;
    const int bx = blockIdx.x * 32, by = blockIdx.y * 32;
#pragma unroll
    for (int k = 0; k < 4; k++) {
        int r = by + ty + k * 8;
        float val = X[(size_t)r * C + bx + tx];
        tile[ty + k * 8][tx] = val;
        Xb[(size_t)r * C + bx + tx] = f2b(val);
    }
    __syncthreads();
#pragma unroll
    for (int k = 0; k < 4; k++) {
        int c = bx + ty + k * 8;
        XbT[(size_t)c * R + by + tx] = f2b(tile[tx][ty + k * 8]);
    }
}

// MT[i*n + j] = (X[j*n + i] != 0)
__global__ __launch_bounds__(256)
void mask_t(const float* __restrict__ X, unsigned char* __restrict__ MT, int n)
{
    __shared__ float tile[32][33];
    const int tx = threadIdx.x, ty = threadIdx.y;
    const int bx = blockIdx.x * 32, by = blockIdx.y * 32;
#pragma unroll
    for (int k = 0; k < 4; k++) {
        int r = by + ty + k * 8;
        tile[ty + k * 8][tx] = X[(size_t)r * n + bx + tx];
    }
    __syncthreads();
#pragma unroll
    for (int k = 0; k < 4; k++) {
        int c = bx + ty + k * 8;
        MT[(size_t)c * n + by + tx] = (tile[tx][ty + k * 8] != 0.f) ? 1 : 0;
    }
}

__global__ __launch_bounds__(256)
void cvtk(const float* __restrict__ X, u16* __restrict__ Y, int n4)
{
    int i = blockIdx.x * 256 + threadIdx.x;
    if (i >= n4) return;
    float4 x = ((const float4*)X)[i];
    ushort4 y;
    y.x = f2b(x.x); y.y = f2b(x.y); y.z = f2b(x.z); y.w = f2b(x.w);
    ((ushort4*)Y)[i] = y;
}

// ---------------------------------------------------------------------------
extern "C" void kernel_launch(void* const* d_in, const int* in_sizes, int n_in,
                              void* d_out, int out_size, void* d_ws, size_t ws_size,
                              hipStream_t stream)
{
    const float* L      = (const float*)d_in[0];
    const float* H      = (const float*)d_in[1];
    const float* B_low  = (const float*)d_in[2];
    const float* H_low  = (const float*)d_in[3];
    const float* B_high = (const float*)d_in[4];
    const float* H_high = (const float*)d_in[5];
    const float* W      = (const float*)d_in[6];
    const float* bvec   = (const float*)d_in[7];
    float* out = (float*)d_out;

    const size_t MB = 1024 * 1024;
    char* ws = (char*)d_ws;
    u16* Sb    = (u16*)(ws + 0);          // 32 MB  scores / attn (bf16, in-place)
    u16* Hb    = (u16*)(ws + 32 * MB);    // 8 MB
    u16* Hlb   = (u16*)(ws + 40 * MB);    // 8 MB
    u16* Hhb   = (u16*)(ws + 48 * MB);    // 8 MB
    u16* HbT   = (u16*)(ws + 56 * MB);    // 8 MB
    u16* HlbT  = (u16*)(ws + 64 * MB);    // 8 MB
    u16* HhbT  = (u16*)(ws + 72 * MB);    // 8 MB
    u16* Wb    = (u16*)(ws + 80 * MB);    // 6 MB
    unsigned char* mlT = (unsigned char*)(ws + 88 * MB); // 16 MB
    u16* H4b   = (u16*)(ws + 104 * MB);   // 24 MB  -> total 128 MB

    dim3 bt(32, 8);
    cvt_t<<<dim3(DF / 32, NS / 32), bt, 0, stream>>>(H,      Hb,  HbT,  NS, DF);
    cvt_t<<<dim3(DF / 32, NS / 32), bt, 0, stream>>>(H_low,  Hlb, HlbT, NS, DF);
    cvt_t<<<dim3(DF / 32, NS / 32), bt, 0, stream>>>(H_high, Hhb, HhbT, NS, DF);
    cvtk<<<(DF * 3 * DF / 4 + 255) / 256, 256, 0, stream>>>(W, Wb, DF * 3 * DF / 4);
    mask_t<<<dim3(NS / 32, NS / 32), bt, 0, stream>>>(B_low, mlT, NS);

    const u16* KVb[3]  = {Hb,  Hlb,  Hhb};
    const u16* KVbT[3] = {HbT, HlbT, HhbT};
    const float* mFs[3] = {L, nullptr, B_high};

    for (int br = 0; br < 3; br++) {
        // S = (H @ KV^T) / 32   -> Sb bf16
        gemm_nt<0><<<dim3(NS / 128, NS / 128), 256, 0, stream>>>(
            Hb, KVb[br], Sb, nullptr, DF, DF, DF, NS, 0.03125f);
        // double softmax with mask, in place
        dsoftmax<<<NS, 256, 0, stream>>>(Sb, mFs[br], br == 1 ? mlT : nullptr);
        // H_br = A2 @ KV  (B operand = KV^T, row-major [DF, NS])
        gemm_nt<0><<<dim3(DF / 128, NS / 128), 256, 0, stream>>>(
            Sb, KVbT[br], H4b + br * DF, nullptr, NS, NS, NS, 3 * DF, 1.0f);
    }
    // out = tanh(H4 @ W^T + b)
    gemm_nt<1><<<dim3(DF / 128, NS / 128), 256, 0, stream>>>(
        H4b, Wb, out, bvec, 3 * DF, 3 * DF, 3 * DF, DF, 1.0f);
}

// Round 2
// 694.459 us; speedup vs baseline: 1.1106x; 1.1106x over previous
//
#include <hip/hip_runtime.h>

// ---------------------------------------------------------------------------
// SimplicialAttentionLayer2 on MI355X (gfx950)
// N=4096, D=1024.  3x: S=(H@KV^T)/32 -> softmax -> *mask -> softmax -> @KV
// out = tanh(concat(H1,H2,H3) @ W^T + b)
// All GEMMs bf16 MFMA 16x16x32, 128x128 tile, BK=64, global_load_lds w=16,
// XOR-swizzled LDS. Independent GEMMs are FUSED into one launch (block-id
// routing) so no 256-block GEMM runs alone (occupancy was the bottleneck:
// MfmaUtil 12%, Occupancy 11% on the A@KV launches).
// Final projection is K-split into 3 partials (P = H_br @ W_br^T) so it can
// pair with the last A@KV; concat buffer never materialized.
// ---------------------------------------------------------------------------

typedef unsigned short u16;
typedef unsigned int u32;
typedef __attribute__((ext_vector_type(8))) short short8;
typedef __attribute__((ext_vector_type(4))) float floatx4;

#define NS 4096
#define DF 1024

__device__ __forceinline__ u16 f2b(float x) {          // fp32 -> bf16 RNE
    u32 u = __float_as_uint(x);
    u32 r = (u + 0x7fffu + ((u >> 16) & 1u)) >> 16;
    return (u16)r;
}
__device__ __forceinline__ u32 packb(float a, float b) {
    return (u32)f2b(a) | ((u32)f2b(b) << 16);
}
__device__ __forceinline__ void unpack8(uint4 u, float* v) {
    v[0] = __uint_as_float(u.x << 16); v[1] = __uint_as_float(u.x & 0xffff0000u);
    v[2] = __uint_as_float(u.y << 16); v[3] = __uint_as_float(u.y & 0xffff0000u);
    v[4] = __uint_as_float(u.z << 16); v[5] = __uint_as_float(u.z & 0xffff0000u);
    v[6] = __uint_as_float(u.w << 16); v[7] = __uint_as_float(u.w & 0xffff0000u);
}

// ---------------------------------------------------------------------------
// Multi-GEMM: up to 3 independent NT sub-GEMMs per launch, routed by blockIdx.
// C[M,N] = epi(alpha * A[M,K] @ B[N,K]^T)
//   epi 0: bf16 store (alpha applied)
//   epi 1: fp32 store raw acc
//   epi 2: fp32 store tanh(acc + P0[idx] + P1[idx] + bias[col])
// ---------------------------------------------------------------------------
struct GemmDesc {
    const u16* A; const u16* B; void* C;
    const float* P0; const float* P1; const float* bias;
    int K, lda, ldb, ldc, nTilesX, nBlocks, epi;
    float alpha;
};

__device__ __forceinline__ void gemm_body(const GemmDesc& d, int bid)
{
    __shared__ u16 As[128 * 64];
    __shared__ u16 Bs[128 * 64];

    const int tid  = threadIdx.x;
    const int wave = tid >> 6;
    const int lane = tid & 63;
    const int bn = bid % d.nTilesX, bm = bid / d.nTilesX;
    const int wm = wave >> 1, wn = wave & 1;
    const int q = lane >> 4, r16 = lane & 15;

    floatx4 acc[4][4];
#pragma unroll
    for (int i = 0; i < 4; i++)
#pragma unroll
        for (int j = 0; j < 4; j++) acc[i][j] = (floatx4){0.f, 0.f, 0.f, 0.f};

    const u16* Abase = d.A + (size_t)bm * 128 * d.lda;
    const u16* Bbase = d.B + (size_t)bn * 128 * d.ldb;
    const int lda = d.lda, ldb = d.ldb, K = d.K;

    for (int kt = 0; kt < K; kt += 64) {
        // stage tiles: LDS phys chunk c' at row holds logical chunk c'^(row&7)
#pragma unroll
        for (int i = 0; i < 4; i++) {
            int chunk = i * 256 + wave * 64 + lane;     // 16B chunk id
            int row   = chunk >> 3;                     // 8 chunks per 128B row
            int clog  = (chunk & 7) ^ (row & 7);
            const u16* ga = Abase + (size_t)row * lda + kt + clog * 8;
            const u16* gb = Bbase + (size_t)row * ldb + kt + clog * 8;
            __builtin_amdgcn_global_load_lds(
                (const __attribute__((address_space(1))) void*)ga,
                (__attribute__((address_space(3))) void*)&As[(i * 256 + wave * 64) * 8],
                16, 0, 0);
            __builtin_amdgcn_global_load_lds(
                (const __attribute__((address_space(1))) void*)gb,
                (__attribute__((address_space(3))) void*)&Bs[(i * 256 + wave * 64) * 8],
                16, 0, 0);
        }
        __syncthreads();

#pragma unroll
        for (int kk = 0; kk < 2; kk++) {
            short8 af[4], bfv[4];
#pragma unroll
            for (int mi = 0; mi < 4; mi++) {
                int row  = wm * 64 + mi * 16 + r16;     // A: m = lane&15
                int phys = (kk * 4 + q) ^ (row & 7);
                af[mi] = *(const short8*)&As[row * 64 + phys * 8];
            }
#pragma unroll
            for (int ni = 0; ni < 4; ni++) {
                int row  = wn * 64 + ni * 16 + r16;     // B: n = lane&15
                int phys = (kk * 4 + q) ^ (row & 7);
                bfv[ni] = *(const short8*)&Bs[row * 64 + phys * 8];
            }
#pragma unroll
            for (int mi = 0; mi < 4; mi++)
#pragma unroll
                for (int ni = 0; ni < 4; ni++)
                    acc[mi][ni] = __builtin_amdgcn_mfma_f32_16x16x32_bf16(
                        af[mi], bfv[ni], acc[mi][ni], 0, 0, 0);
        }
        __syncthreads();
    }

    // epilogue: D element (row = q*4 + r, col = lane&15)
#pragma unroll
    for (int mi = 0; mi < 4; mi++) {
#pragma unroll
        for (int ni = 0; ni < 4; ni++) {
            floatx4 v = acc[mi][ni];
            int col  = bn * 128 + wn * 64 + ni * 16 + r16;
            int rowb = bm * 128 + wm * 64 + mi * 16 + q * 4;
            if (d.epi == 0) {
                u16* C = (u16*)d.C;
#pragma unroll
                for (int r = 0; r < 4; r++)
                    C[(size_t)(rowb + r) * d.ldc + col] = f2b(v[r] * d.alpha);
            } else if (d.epi == 1) {
                float* C = (float*)d.C;
#pragma unroll
                for (int r = 0; r < 4; r++)
                    C[(size_t)(rowb + r) * d.ldc + col] = v[r];
            } else {
                float* C = (float*)d.C;
                float bb = d.bias[col];
#pragma unroll
                for (int r = 0; r < 4; r++) {
                    size_t idx = (size_t)(rowb + r) * d.ldc + col;
                    C[idx] = tanhf(v[r] + d.P0[idx] + d.P1[idx] + bb);
                }
            }
        }
    }
}

__global__ __launch_bounds__(256)
void mgemm(GemmDesc d0, GemmDesc d1, GemmDesc d2)
{
    int bid = blockIdx.x;
    if (bid < d0.nBlocks)                 { gemm_body(d0, bid); return; }
    bid -= d0.nBlocks;
    if (bid < d1.nBlocks)                 { gemm_body(d1, bid); return; }
    bid -= d1.nBlocks;
    gemm_body(d2, bid);
}

// ---------------------------------------------------------------------------
// Double softmax over one row of S (bf16, in-place), with mask multiply.
// mF: fp32 mask source row-major (mask = src != 0), or null -> bit mask mB
// (mB[row*128 + w], bit j of word w = column w*32+j).
// ---------------------------------------------------------------------------
__device__ __forceinline__ float blockMax(float x, volatile float* red) {
#pragma unroll
    for (int off = 32; off > 0; off >>= 1) x = fmaxf(x, __shfl_xor(x, off, 64));
    __syncthreads();
    if ((threadIdx.x & 63) == 0) red[threadIdx.x >> 6] = x;
    __syncthreads();
    return fmaxf(fmaxf(red[0], red[1]), fmaxf(red[2], red[3]));
}
__device__ __forceinline__ float blockSum(float x, volatile float* red) {
#pragma unroll
    for (int off = 32; off > 0; off >>= 1) x += __shfl_xor(x, off, 64);
    __syncthreads();
    if ((threadIdx.x & 63) == 0) red[threadIdx.x >> 6] = x;
    __syncthreads();
    return red[0] + red[1] + red[2] + red[3];
}

__global__ __launch_bounds__(256)
void dsoftmax(u16* __restrict__ S, const float* __restrict__ mF,
              const u32* __restrict__ mB)
{
    __shared__ float red[4];
    const int row = blockIdx.x;
    const int t   = threadIdx.x;
    u16* Srow = S + (size_t)row * NS;

    float v[16];
    uint4 u0 = ((const uint4*)Srow)[t * 2];
    uint4 u1 = ((const uint4*)Srow)[t * 2 + 1];
    unpack8(u0, v); unpack8(u1, v + 8);

    float m = -1e30f;
#pragma unroll
    for (int j = 0; j < 16; j++) m = fmaxf(m, v[j]);
    m = blockMax(m, red);

    float s = 0.f;
#pragma unroll
    for (int j = 0; j < 16; j++) { v[j] = __expf(v[j] - m); s += v[j]; }
    s = blockSum(s, red);
    float rz = 1.0f / s;

    float v2[16];
    if (mF) {
        const float* mrow = mF + (size_t)row * NS;
#pragma unroll
        for (int k = 0; k < 4; k++) {
            float4 mv = ((const float4*)mrow)[t * 4 + k];
            v2[k * 4 + 0] = (mv.x != 0.f) ? v[k * 4 + 0] * rz : 0.f;
            v2[k * 4 + 1] = (mv.y != 0.f) ? v[k * 4 + 1] * rz : 0.f;
            v2[k * 4 + 2] = (mv.z != 0.f) ? v[k * 4 + 2] * rz : 0.f;
            v2[k * 4 + 3] = (mv.w != 0.f) ? v[k * 4 + 3] * rz : 0.f;
        }
    } else {
        u32 w = mB[(size_t)row * (NS / 32) + (t >> 1)];
        u32 half = (w >> ((t & 1) * 16)) & 0xffffu;
#pragma unroll
        for (int j = 0; j < 16; j++)
            v2[j] = ((half >> j) & 1u) ? v[j] * rz : 0.f;
    }

    // second softmax: masked entries are logit 0 (still contribute exp)
    float m2 = -1e30f;
#pragma unroll
    for (int j = 0; j < 16; j++) m2 = fmaxf(m2, v2[j]);
    m2 = blockMax(m2, red);
    float s2 = 0.f;
#pragma unroll
    for (int j = 0; j < 16; j++) { v2[j] = __expf(v2[j] - m2); s2 += v2[j]; }
    s2 = blockSum(s2, red);
    float rz2 = 1.0f / s2;

    uint4 o0, o1;
    o0.x = packb(v2[0] * rz2,  v2[1] * rz2);
    o0.y = packb(v2[2] * rz2,  v2[3] * rz2);
    o0.z = packb(v2[4] * rz2,  v2[5] * rz2);
    o0.w = packb(v2[6] * rz2,  v2[7] * rz2);
    o1.x = packb(v2[8] * rz2,  v2[9] * rz2);
    o1.y = packb(v2[10] * rz2, v2[11] * rz2);
    o1.z = packb(v2[12] * rz2, v2[13] * rz2);
    o1.w = packb(v2[14] * rz2, v2[15] * rz2);
    ((uint4*)Srow)[t * 2]     = o0;
    ((uint4*)Srow)[t * 2 + 1] = o1;
}

// ---------------------------------------------------------------------------
// fp32 [R,C] -> bf16 [R,C] and bf16 transposed [C,R]
// ---------------------------------------------------------------------------
__global__ __launch_bounds__(256)
void cvt_t(const float* __restrict__ X, u16* __restrict__ Xb, u16* __restrict__ XbT,
           int R, int C)
{
    __shared__ float tile[32][33];
    const int tx = threadIdx.x, ty = threadIdx.y;
    const int bx = blockIdx.x * 32, by = blockIdx.y * 32;
#pragma unroll
    for (int k = 0; k < 4; k++) {
        int r = by + ty + k * 8;
        float val = X[(size_t)r * C + bx + tx];
        tile[ty + k * 8][tx] = val;
        Xb[(size_t)r * C + bx + tx] = f2b(val);
    }
    __syncthreads();
#pragma unroll
    for (int k = 0; k < 4; k++) {
        int c = bx + ty + k * 8;
        XbT[(size_t)c * R + by + tx] = f2b(tile[tx][ty + k * 8]);
    }
}

// bit-packed transposed nonzero mask: MT[c*(n/32)+w] bit b = (X[w*32+b][c]!=0)
__global__ __launch_bounds__(256)
void mask_bits(const float* __restrict__ X, u32* __restrict__ MT, int n)
{
    __shared__ float tile[32][33];
    const int tx = threadIdx.x, ty = threadIdx.y;
    const int bx = blockIdx.x * 32, by = blockIdx.y * 32;
#pragma unroll
    for (int k = 0; k < 4; k++) {
        int r = by + ty + k * 8;
        tile[ty + k * 8][tx] = X[(size_t)r * n + bx + tx];
    }
    __syncthreads();
#pragma unroll
    for (int k = 0; k < 4; k++) {
        int c = bx + ty + k * 8;
        // lane = (ty&1)*32 + tx within the wave; ballot collects both columns
        unsigned long long m = __ballot(tile[tx][ty + k * 8] != 0.f);
        u32 w = (ty & 1) ? (u32)(m >> 32) : (u32)m;
        if (tx == 0) MT[(size_t)c * (n / 32) + (by >> 5)] = w;
    }
}

__global__ __launch_bounds__(256)
void cvtk(const float* __restrict__ X, u16* __restrict__ Y, int n4)
{
    int i = blockIdx.x * 256 + threadIdx.x;
    if (i >= n4) return;
    float4 x = ((const float4*)X)[i];
    ushort4 y;
    y.x = f2b(x.x); y.y = f2b(x.y); y.z = f2b(x.z); y.w = f2b(x.w);
    ((ushort4*)Y)[i] = y;
}

// ---------------------------------------------------------------------------
static inline GemmDesc mkdesc(const u16* A, const u16* B, void* C,
                              int K, int lda, int ldb, int ldc,
                              int nTilesX, int nTilesY, int epi, float alpha,
                              const float* P0 = nullptr, const float* P1 = nullptr,
                              const float* bias = nullptr)
{
    GemmDesc d;
    d.A = A; d.B = B; d.C = C; d.P0 = P0; d.P1 = P1; d.bias = bias;
    d.K = K; d.lda = lda; d.ldb = ldb; d.ldc = ldc;
    d.nTilesX = nTilesX; d.nBlocks = nTilesX * nTilesY; d.epi = epi;
    d.alpha = alpha;
    return d;
}

extern "C" void kernel_launch(void* const* d_in, const int* in_sizes, int n_in,
                              void* d_out, int out_size, void* d_ws, size_t ws_size,
                              hipStream_t stream)
{
    const float* L      = (const float*)d_in[0];
    const float* H      = (const float*)d_in[1];
    const float* B_low  = (const float*)d_in[2];
    const float* H_low  = (const float*)d_in[3];
    const float* B_high = (const float*)d_in[4];
    const float* H_high = (const float*)d_in[5];
    const float* W      = (const float*)d_in[6];
    const float* bvec   = (const float*)d_in[7];
    float* out = (float*)d_out;

    // 128 MB workspace layout with lifetime overlap:
    const size_t MB = 1024 * 1024;
    char* ws = (char*)d_ws;
    u16* S_A   = (u16*)(ws + 0);          // 32 MB  scores A
    u16* S_B   = (u16*)(ws + 32 * MB);    // 32 MB  scores B; dead after G2 ->
    float* P0  = (float*)(ws + 32 * MB);  //   16 MB fp32 partial 0
    float* P1  = (float*)(ws + 48 * MB);  //   16 MB fp32 partial 1
    u16* Hb    = (u16*)(ws + 64 * MB);    // 8 MB   (A of all S-gemms; B of br0)
    u16* Hlb   = (u16*)(ws + 72 * MB);    // 8 MB   (B of br1, dead after G1) ->
    u16* Hc1   = (u16*)(ws + 72 * MB);    //   H_br1 (written G2, read G3)
    u16* Hhb   = (u16*)(ws + 80 * MB);    // 8 MB   (B of br2, dead after G2) ->
    u16* Hc2   = (u16*)(ws + 80 * MB);    //   H_br2 (written G3, read G4)
    u16* HbT   = (u16*)(ws + 88 * MB);    // 8 MB
    u16* HlbT  = (u16*)(ws + 96 * MB);    // 8 MB
    u16* HhbT  = (u16*)(ws + 104 * MB);   // 8 MB
    u16* Wb    = (u16*)(ws + 112 * MB);   // 6 MB
    u32* mlT   = (u32*)(ws + 118 * MB);   // 2 MB bit mask (B_low^T != 0)
    u16* Hc0   = (u16*)(ws + 120 * MB);   // 8 MB   H_br0 (written G1, read G3)

    dim3 bt(32, 8);
    cvt_t<<<dim3(DF / 32, NS / 32), bt, 0, stream>>>(H,      Hb,  HbT,  NS, DF);
    cvt_t<<<dim3(DF / 32, NS / 32), bt, 0, stream>>>(H_low,  Hlb, HlbT, NS, DF);
    cvt_t<<<dim3(DF / 32, NS / 32), bt, 0, stream>>>(H_high, Hhb, HhbT, NS, DF);
    cvtk<<<(DF * 3 * DF / 4 + 255) / 256, 256, 0, stream>>>(W, Wb, DF * 3 * DF / 4);
    mask_bits<<<dim3(NS / 32, NS / 32), bt, 0, stream>>>(B_low, mlT, NS);

    GemmDesc z = {};  // unused slots

    // G0: S0 = (H @ H^T)/32                              [1024 blocks]
    GemmDesc s0 = mkdesc(Hb, Hb, S_A, DF, DF, DF, NS, NS / 128, NS / 128, 0, 0.03125f);
    mgemm<<<s0.nBlocks, 256, 0, stream>>>(s0, z, z);
    dsoftmax<<<NS, 256, 0, stream>>>(S_A, L, nullptr);

    // G1: A@KV(br0) [256, K=4096, long-K first] + Sgemm(br1) [1024]
    GemmDesc a0 = mkdesc(S_A, HbT, Hc0, NS, NS, NS, DF, DF / 128, NS / 128, 0, 1.0f);
    GemmDesc s1 = mkdesc(Hb, Hlb, S_B, DF, DF, DF, NS, NS / 128, NS / 128, 0, 0.03125f);
    mgemm<<<a0.nBlocks + s1.nBlocks, 256, 0, stream>>>(a0, s1, z);
    dsoftmax<<<NS, 256, 0, stream>>>(S_B, nullptr, mlT);

    // G2: A@KV(br1) + Sgemm(br2)
    GemmDesc a1 = mkdesc(S_B, HlbT, Hc1, NS, NS, NS, DF, DF / 128, NS / 128, 0, 1.0f);
    GemmDesc s2 = mkdesc(Hb, Hhb, S_A, DF, DF, DF, NS, NS / 128, NS / 128, 0, 0.03125f);
    mgemm<<<a1.nBlocks + s2.nBlocks, 256, 0, stream>>>(a1, s2, z);
    dsoftmax<<<NS, 256, 0, stream>>>(S_A, B_high, nullptr);

    // G3: A@KV(br2) + P0 = Hc0 @ W0^T + P1 = Hc1 @ W1^T   [768 blocks]
    GemmDesc a2 = mkdesc(S_A, HhbT, Hc2, NS, NS, NS, DF, DF / 128, NS / 128, 0, 1.0f);
    GemmDesc w0 = mkdesc(Hc0, Wb,           P0, DF, DF, 3 * DF, DF, DF / 128, NS / 128, 1, 1.0f);
    GemmDesc w1 = mkdesc(Hc1, Wb + DF,      P1, DF, DF, 3 * DF, DF, DF / 128, NS / 128, 1, 1.0f);
    mgemm<<<a2.nBlocks + w0.nBlocks + w1.nBlocks, 256, 0, stream>>>(a2, w0, w1);

    // G4: out = tanh(Hc2 @ W2^T + P0 + P1 + b)            [256 blocks, K=1024]
    GemmDesc w2 = mkdesc(Hc2, Wb + 2 * DF, out, DF, DF, 3 * DF, DF, DF / 128, NS / 128, 2, 1.0f,
                         P0, P1, bvec);
    mgemm<<<w2.nBlocks, 256, 0, stream>>>(w2, z, z);
}

// Round 3
// 689.749 us; speedup vs baseline: 1.1182x; 1.0068x over previous
//
#include <hip/hip_runtime.h>

// ---------------------------------------------------------------------------
// SimplicialAttentionLayer2 on MI355X (gfx950)
// N=4096, D=1024.  3x: S=(H@KV^T)/32 -> softmax -> *mask -> softmax -> @KV
// out = tanh(concat(H1,H2,H3) @ W^T + b)
// R3: uniform-work launches. All three S-gemms fused into ONE M=4096,N=12288
// GEMM (3072 uniform blocks); all three A@KV in one launch (768 uniform
// K=4096 blocks); final projection split-K into 3 uniform K=1024 descs +
// fp32 partials + tanh-combine. R2's imbalance (1 long + 4 short blocks/CU,
// MfmaUtil 15.8%) is eliminated. Needs 176 MB ws; falls back to R2 schedule
// if ws_size is smaller.
// ---------------------------------------------------------------------------

typedef unsigned short u16;
typedef unsigned int u32;
typedef __attribute__((ext_vector_type(8))) short short8;
typedef __attribute__((ext_vector_type(4))) float floatx4;

#define NS 4096
#define DF 1024

__device__ __forceinline__ u16 f2b(float x) {          // fp32 -> bf16 RNE
    u32 u = __float_as_uint(x);
    u32 r = (u + 0x7fffu + ((u >> 16) & 1u)) >> 16;
    return (u16)r;
}
__device__ __forceinline__ u32 packb(float a, float b) {
    return (u32)f2b(a) | ((u32)f2b(b) << 16);
}
__device__ __forceinline__ void unpack8(uint4 u, float* v) {
    v[0] = __uint_as_float(u.x << 16); v[1] = __uint_as_float(u.x & 0xffff0000u);
    v[2] = __uint_as_float(u.y << 16); v[3] = __uint_as_float(u.y & 0xffff0000u);
    v[4] = __uint_as_float(u.z << 16); v[5] = __uint_as_float(u.z & 0xffff0000u);
    v[6] = __uint_as_float(u.w << 16); v[7] = __uint_as_float(u.w & 0xffff0000u);
}

// ---------------------------------------------------------------------------
// Multi-GEMM: up to 3 independent NT sub-GEMMs per launch, routed by blockIdx.
// C[M,N] = epi(alpha * A[M,K] @ B[N,K]^T)
//   epi 0: bf16 store (alpha applied)
//   epi 1: fp32 store raw acc
//   epi 2: fp32 store tanh(acc + P0[idx] + P1[idx] + bias[col])
// ---------------------------------------------------------------------------
struct GemmDesc {
    const u16* A; const u16* B; void* C;
    const float* P0; const float* P1; const float* bias;
    int K, lda, ldb, ldc, nTilesX, nBlocks, epi;
    float alpha;
};

__device__ __forceinline__ void gemm_body(const GemmDesc& d, int bid)
{
    __shared__ u16 As[128 * 64];
    __shared__ u16 Bs[128 * 64];

    const int tid  = threadIdx.x;
    const int wave = tid >> 6;
    const int lane = tid & 63;
    const int bn = bid % d.nTilesX, bm = bid / d.nTilesX;
    const int wm = wave >> 1, wn = wave & 1;
    const int q = lane >> 4, r16 = lane & 15;

    floatx4 acc[4][4];
#pragma unroll
    for (int i = 0; i < 4; i++)
#pragma unroll
        for (int j = 0; j < 4; j++) acc[i][j] = (floatx4){0.f, 0.f, 0.f, 0.f};

    const u16* Abase = d.A + (size_t)bm * 128 * d.lda;
    const u16* Bbase = d.B + (size_t)bn * 128 * d.ldb;
    const int lda = d.lda, ldb = d.ldb, K = d.K;

    for (int kt = 0; kt < K; kt += 64) {
        // stage tiles: LDS phys chunk c' at row holds logical chunk c'^(row&7)
#pragma unroll
        for (int i = 0; i < 4; i++) {
            int chunk = i * 256 + wave * 64 + lane;     // 16B chunk id
            int row   = chunk >> 3;                     // 8 chunks per 128B row
            int clog  = (chunk & 7) ^ (row & 7);
            const u16* ga = Abase + (size_t)row * lda + kt + clog * 8;
            const u16* gb = Bbase + (size_t)row * ldb + kt + clog * 8;
            __builtin_amdgcn_global_load_lds(
                (const __attribute__((address_space(1))) void*)ga,
                (__attribute__((address_space(3))) void*)&As[(i * 256 + wave * 64) * 8],
                16, 0, 0);
            __builtin_amdgcn_global_load_lds(
                (const __attribute__((address_space(1))) void*)gb,
                (__attribute__((address_space(3))) void*)&Bs[(i * 256 + wave * 64) * 8],
                16, 0, 0);
        }
        __syncthreads();

#pragma unroll
        for (int kk = 0; kk < 2; kk++) {
            short8 af[4], bfv[4];
#pragma unroll
            for (int mi = 0; mi < 4; mi++) {
                int row  = wm * 64 + mi * 16 + r16;     // A: m = lane&15
                int phys = (kk * 4 + q) ^ (row & 7);
                af[mi] = *(const short8*)&As[row * 64 + phys * 8];
            }
#pragma unroll
            for (int ni = 0; ni < 4; ni++) {
                int row  = wn * 64 + ni * 16 + r16;     // B: n = lane&15
                int phys = (kk * 4 + q) ^ (row & 7);
                bfv[ni] = *(const short8*)&Bs[row * 64 + phys * 8];
            }
#pragma unroll
            for (int mi = 0; mi < 4; mi++)
#pragma unroll
                for (int ni = 0; ni < 4; ni++)
                    acc[mi][ni] = __builtin_amdgcn_mfma_f32_16x16x32_bf16(
                        af[mi], bfv[ni], acc[mi][ni], 0, 0, 0);
        }
        __syncthreads();
    }

    // epilogue: D element (row = q*4 + r, col = lane&15)
#pragma unroll
    for (int mi = 0; mi < 4; mi++) {
#pragma unroll
        for (int ni = 0; ni < 4; ni++) {
            floatx4 v = acc[mi][ni];
            int col  = bn * 128 + wn * 64 + ni * 16 + r16;
            int rowb = bm * 128 + wm * 64 + mi * 16 + q * 4;
            if (d.epi == 0) {
                u16* C = (u16*)d.C;
#pragma unroll
                for (int r = 0; r < 4; r++)
                    C[(size_t)(rowb + r) * d.ldc + col] = f2b(v[r] * d.alpha);
            } else if (d.epi == 1) {
                float* C = (float*)d.C;
#pragma unroll
                for (int r = 0; r < 4; r++)
                    C[(size_t)(rowb + r) * d.ldc + col] = v[r];
            } else {
                float* C = (float*)d.C;
                float bb = d.bias[col];
#pragma unroll
                for (int r = 0; r < 4; r++) {
                    size_t idx = (size_t)(rowb + r) * d.ldc + col;
                    C[idx] = tanhf(v[r] + d.P0[idx] + d.P1[idx] + bb);
                }
            }
        }
    }
}

__global__ __launch_bounds__(256)
void mgemm(GemmDesc d0, GemmDesc d1, GemmDesc d2)
{
    int bid = blockIdx.x;
    if (bid < d0.nBlocks)                 { gemm_body(d0, bid); return; }
    bid -= d0.nBlocks;
    if (bid < d1.nBlocks)                 { gemm_body(d1, bid); return; }
    bid -= d1.nBlocks;
    gemm_body(d2, bid);
}

// ---------------------------------------------------------------------------
// Double softmax, branch-routed: grid = nbr*4096 blocks; branch = bid>>12.
// Each row is 4096 bf16 at stride ldS, in-place. Mask: fp32 mF (!=0) or bit
// mask mB (mB[row*128+w], bit j = column w*32+j).
// ---------------------------------------------------------------------------
struct SmDesc { u16* S; const float* mF; const u32* mB; };

__device__ __forceinline__ float blockMax(float x, volatile float* red) {
#pragma unroll
    for (int off = 32; off > 0; off >>= 1) x = fmaxf(x, __shfl_xor(x, off, 64));
    __syncthreads();
    if ((threadIdx.x & 63) == 0) red[threadIdx.x >> 6] = x;
    __syncthreads();
    return fmaxf(fmaxf(red[0], red[1]), fmaxf(red[2], red[3]));
}
__device__ __forceinline__ float blockSum(float x, volatile float* red) {
#pragma unroll
    for (int off = 32; off > 0; off >>= 1) x += __shfl_xor(x, off, 64);
    __syncthreads();
    if ((threadIdx.x & 63) == 0) red[threadIdx.x >> 6] = x;
    __syncthreads();
    return red[0] + red[1] + red[2] + red[3];
}

__global__ __launch_bounds__(256)
void dsoftmax3(SmDesc d0, SmDesc d1, SmDesc d2, int ldS)
{
    __shared__ float red[4];
    const int bid = blockIdx.x;
    const int br  = bid >> 12;
    const int row = bid & 4095;
    const SmDesc d = (br == 0) ? d0 : (br == 1) ? d1 : d2;
    u16* Srow = d.S + (size_t)row * ldS;
    const int t = threadIdx.x;

    float v[16];
    uint4 u0 = ((const uint4*)Srow)[t * 2];
    uint4 u1 = ((const uint4*)Srow)[t * 2 + 1];
    unpack8(u0, v); unpack8(u1, v + 8);

    float m = -1e30f;
#pragma unroll
    for (int j = 0; j < 16; j++) m = fmaxf(m, v[j]);
    m = blockMax(m, red);

    float s = 0.f;
#pragma unroll
    for (int j = 0; j < 16; j++) { v[j] = __expf(v[j] - m); s += v[j]; }
    s = blockSum(s, red);
    float rz = 1.0f / s;

    float v2[16];
    if (d.mF) {
        const float* mrow = d.mF + (size_t)row * NS;
#pragma unroll
        for (int k = 0; k < 4; k++) {
            float4 mv = ((const float4*)mrow)[t * 4 + k];
            v2[k * 4 + 0] = (mv.x != 0.f) ? v[k * 4 + 0] * rz : 0.f;
            v2[k * 4 + 1] = (mv.y != 0.f) ? v[k * 4 + 1] * rz : 0.f;
            v2[k * 4 + 2] = (mv.z != 0.f) ? v[k * 4 + 2] * rz : 0.f;
            v2[k * 4 + 3] = (mv.w != 0.f) ? v[k * 4 + 3] * rz : 0.f;
        }
    } else {
        u32 w = d.mB[(size_t)row * (NS / 32) + (t >> 1)];
        u32 half = (w >> ((t & 1) * 16)) & 0xffffu;
#pragma unroll
        for (int j = 0; j < 16; j++)
            v2[j] = ((half >> j) & 1u) ? v[j] * rz : 0.f;
    }

    // second softmax: masked entries are logit 0 (still contribute exp)
    float m2 = -1e30f;
#pragma unroll
    for (int j = 0; j < 16; j++) m2 = fmaxf(m2, v2[j]);
    m2 = blockMax(m2, red);
    float s2 = 0.f;
#pragma unroll
    for (int j = 0; j < 16; j++) { v2[j] = __expf(v2[j] - m2); s2 += v2[j]; }
    s2 = blockSum(s2, red);
    float rz2 = 1.0f / s2;

    uint4 o0, o1;
    o0.x = packb(v2[0] * rz2,  v2[1] * rz2);
    o0.y = packb(v2[2] * rz2,  v2[3] * rz2);
    o0.z = packb(v2[4] * rz2,  v2[5] * rz2);
    o0.w = packb(v2[6] * rz2,  v2[7] * rz2);
    o1.x = packb(v2[8] * rz2,  v2[9] * rz2);
    o1.y = packb(v2[10] * rz2, v2[11] * rz2);
    o1.z = packb(v2[12] * rz2, v2[13] * rz2);
    o1.w = packb(v2[14] * rz2, v2[15] * rz2);
    ((uint4*)Srow)[t * 2]     = o0;
    ((uint4*)Srow)[t * 2 + 1] = o1;
}

// ---------------------------------------------------------------------------
// fp32 [NS,DF] -> bf16 [NS,DF] and bf16 transposed [DF,NS]; 3 inputs via z.
// Xb / XbT are laid as 3 contiguous matrices.
// ---------------------------------------------------------------------------
__global__ __launch_bounds__(256)
void cvt3(const float* __restrict__ X0, const float* __restrict__ X1,
          const float* __restrict__ X2, u16* __restrict__ Xball,
          u16* __restrict__ XbTall)
{
    __shared__ float tile[32][33];
    const float* X = (blockIdx.z == 0) ? X0 : (blockIdx.z == 1) ? X1 : X2;
    u16* Xb  = Xball  + (size_t)blockIdx.z * NS * DF;
    u16* XbT = XbTall + (size_t)blockIdx.z * NS * DF;
    const int tx = threadIdx.x, ty = threadIdx.y;
    const int bx = blockIdx.x * 32, by = blockIdx.y * 32;
#pragma unroll
    for (int k = 0; k < 4; k++) {
        int r = by + ty + k * 8;
        float val = X[(size_t)r * DF + bx + tx];
        tile[ty + k * 8][tx] = val;
        Xb[(size_t)r * DF + bx + tx] = f2b(val);
    }
    __syncthreads();
#pragma unroll
    for (int k = 0; k < 4; k++) {
        int c = bx + ty + k * 8;
        XbT[(size_t)c * NS + by + tx] = f2b(tile[tx][ty + k * 8]);
    }
}

// bit-packed transposed nonzero mask: MT[c*(n/32)+w] bit b = (X[w*32+b][c]!=0)
__global__ __launch_bounds__(256)
void mask_bits(const float* __restrict__ X, u32* __restrict__ MT, int n)
{
    __shared__ float tile[32][33];
    const int tx = threadIdx.x, ty = threadIdx.y;
    const int bx = blockIdx.x * 32, by = blockIdx.y * 32;
#pragma unroll
    for (int k = 0; k < 4; k++) {
        int r = by + ty + k * 8;
        tile[ty + k * 8][tx] = X[(size_t)r * n + bx + tx];
    }
    __syncthreads();
#pragma unroll
    for (int k = 0; k < 4; k++) {
        int c = bx + ty + k * 8;
        unsigned long long m = __ballot(tile[tx][ty + k * 8] != 0.f);
        u32 w = (ty & 1) ? (u32)(m >> 32) : (u32)m;
        if (tx == 0) MT[(size_t)c * (n / 32) + (by >> 5)] = w;
    }
}

__global__ __launch_bounds__(256)
void cvtk(const float* __restrict__ X, u16* __restrict__ Y, int n4)
{
    int i = blockIdx.x * 256 + threadIdx.x;
    if (i >= n4) return;
    float4 x = ((const float4*)X)[i];
    ushort4 y;
    y.x = f2b(x.x); y.y = f2b(x.y); y.z = f2b(x.z); y.w = f2b(x.w);
    ((ushort4*)Y)[i] = y;
}

// out = tanh(P0 + P1 + P2 + bias[col]); 4096x1024 fp32, float4 per thread.
__global__ __launch_bounds__(256)
void combine(const float* __restrict__ P0, const float* __restrict__ P1,
             const float* __restrict__ P2, const float* __restrict__ bias,
             float* __restrict__ out)
{
    int i = blockIdx.x * 256 + threadIdx.x;       // float4 index
    float4 a = ((const float4*)P0)[i];
    float4 b = ((const float4*)P1)[i];
    float4 c = ((const float4*)P2)[i];
    float4 bb = ((const float4*)bias)[i & 255];   // 1024 cols = 256 float4
    float4 o;
    o.x = tanhf(a.x + b.x + c.x + bb.x);
    o.y = tanhf(a.y + b.y + c.y + bb.y);
    o.z = tanhf(a.z + b.z + c.z + bb.z);
    o.w = tanhf(a.w + b.w + c.w + bb.w);
    ((float4*)out)[i] = o;
}

// ---------------------------------------------------------------------------
static inline GemmDesc mkdesc(const u16* A, const u16* B, void* C,
                              int K, int lda, int ldb, int ldc,
                              int nTilesX, int nTilesY, int epi, float alpha,
                              const float* P0 = nullptr, const float* P1 = nullptr,
                              const float* bias = nullptr)
{
    GemmDesc d;
    d.A = A; d.B = B; d.C = C; d.P0 = P0; d.P1 = P1; d.bias = bias;
    d.K = K; d.lda = lda; d.ldb = ldb; d.ldc = ldc;
    d.nTilesX = nTilesX; d.nBlocks = nTilesX * nTilesY; d.epi = epi;
    d.alpha = alpha;
    return d;
}

extern "C" void kernel_launch(void* const* d_in, const int* in_sizes, int n_in,
                              void* d_out, int out_size, void* d_ws, size_t ws_size,
                              hipStream_t stream)
{
    const float* L      = (const float*)d_in[0];
    const float* H      = (const float*)d_in[1];
    const float* B_low  = (const float*)d_in[2];
    const float* H_low  = (const float*)d_in[3];
    const float* B_high = (const float*)d_in[4];
    const float* H_high = (const float*)d_in[5];
    const float* W      = (const float*)d_in[6];
    const float* bvec   = (const float*)d_in[7];
    float* out = (float*)d_out;

    const size_t MB = 1024 * 1024;
    char* ws = (char*)d_ws;
    GemmDesc z = {};
    SmDesc zs = {};
    dim3 bt(32, 8);

    if (ws_size >= 176 * MB) {
        // ---- fused uniform-work schedule (176 MB) ----
        u16* S_all = (u16*)(ws + 0);            // 96 MB [4096,12288] bf16
        float* P0  = (float*)(ws + 0);          //   16 MB (S_all dead)
        float* P1  = (float*)(ws + 16 * MB);
        float* P2  = (float*)(ws + 32 * MB);
        u16* Hcat  = (u16*)(ws + 96 * MB);      // 24 MB [12288,1024] bf16
        u16* HTcat = (u16*)(ws + 120 * MB);     // 24 MB 3x [1024,4096] bf16
        u16* Hc    = (u16*)(ws + 144 * MB);     // 24 MB [4096,3072] bf16
        u16* Wb    = (u16*)(ws + 168 * MB);     // 6 MB
        u32* mlT   = (u32*)(ws + 174 * MB);     // 2 MB

        cvt3<<<dim3(DF / 32, NS / 32, 3), bt, 0, stream>>>(H, H_low, H_high, Hcat, HTcat);
        cvtk<<<(DF * 3 * DF / 4 + 255) / 256, 256, 0, stream>>>(W, Wb, DF * 3 * DF / 4);
        mask_bits<<<dim3(NS / 32, NS / 32), bt, 0, stream>>>(B_low, mlT, NS);

        // S_all = (H @ [H;H_low;H_high]^T)/32   [3072 uniform blocks]
        GemmDesc sg = mkdesc(Hcat, Hcat, S_all, DF, DF, DF, 3 * NS,
                             3 * NS / 128, NS / 128, 0, 0.03125f);
        mgemm<<<sg.nBlocks, 256, 0, stream>>>(sg, z, z);

        // fused double softmax over 12288 rows
        SmDesc s0 = {S_all,            L,      nullptr};
        SmDesc s1 = {S_all + NS,       nullptr, mlT};
        SmDesc s2 = {S_all + 2 * NS,   B_high, nullptr};
        dsoftmax3<<<3 * NS, 256, 0, stream>>>(s0, s1, s2, 3 * NS);

        // Hc[:, b*1024:(b+1)*1024] = A_b @ KV_b   [768 uniform K=4096 blocks]
        GemmDesc a0 = mkdesc(S_all,          HTcat,               Hc,          NS, 3 * NS, NS, 3 * DF, DF / 128, NS / 128, 0, 1.0f);
        GemmDesc a1 = mkdesc(S_all + NS,     HTcat + NS * DF,     Hc + DF,     NS, 3 * NS, NS, 3 * DF, DF / 128, NS / 128, 0, 1.0f);
        GemmDesc a2 = mkdesc(S_all + 2 * NS, HTcat + 2 * NS * DF, Hc + 2 * DF, NS, 3 * NS, NS, 3 * DF, DF / 128, NS / 128, 0, 1.0f);
        mgemm<<<a0.nBlocks + a1.nBlocks + a2.nBlocks, 256, 0, stream>>>(a0, a1, a2);

        // P_b = Hc_b @ W_b^T (fp32 partials)     [768 uniform K=1024 blocks]
        GemmDesc w0 = mkdesc(Hc,          Wb,          P0, DF, 3 * DF, 3 * DF, DF, DF / 128, NS / 128, 1, 1.0f);
        GemmDesc w1 = mkdesc(Hc + DF,     Wb + DF,     P1, DF, 3 * DF, 3 * DF, DF, DF / 128, NS / 128, 1, 1.0f);
        GemmDesc w2 = mkdesc(Hc + 2 * DF, Wb + 2 * DF, P2, DF, 3 * DF, 3 * DF, DF, DF / 128, NS / 128, 1, 1.0f);
        mgemm<<<w0.nBlocks + w1.nBlocks + w2.nBlocks, 256, 0, stream>>>(w0, w1, w2);

        // out = tanh(P0+P1+P2+b)
        combine<<<NS * DF / 4 / 256, 256, 0, stream>>>(P0, P1, P2, bvec, out);
        return;
    }

    // ---- fallback: R2 pipelined schedule (128 MB) ----
    u16* S_A   = (u16*)(ws + 0);          // 32 MB
    u16* S_B   = (u16*)(ws + 32 * MB);    // 32 MB; dead after G2 ->
    float* P0  = (float*)(ws + 32 * MB);  //   16 MB
    float* P1  = (float*)(ws + 48 * MB);  //   16 MB
    u16* Hb    = (u16*)(ws + 64 * MB);    // 8 MB
    u16* Hlb   = (u16*)(ws + 72 * MB);    // 8 MB -> Hc1
    u16* Hc1   = (u16*)(ws + 72 * MB);
    u16* Hhb   = (u16*)(ws + 80 * MB);    // 8 MB -> Hc2
    u16* Hc2   = (u16*)(ws + 80 * MB);
    u16* HbT   = (u16*)(ws + 88 * MB);
    u16* HlbT  = (u16*)(ws + 96 * MB);
    u16* HhbT  = (u16*)(ws + 104 * MB);
    u16* Wb    = (u16*)(ws + 112 * MB);
    u32* mlT   = (u32*)(ws + 118 * MB);
    u16* Hc0   = (u16*)(ws + 120 * MB);

    cvt3<<<dim3(DF / 32, NS / 32, 3), bt, 0, stream>>>(H, H_low, H_high, Hb, HbT);
    cvtk<<<(DF * 3 * DF / 4 + 255) / 256, 256, 0, stream>>>(W, Wb, DF * 3 * DF / 4);
    mask_bits<<<dim3(NS / 32, NS / 32), bt, 0, stream>>>(B_low, mlT, NS);

    GemmDesc s0 = mkdesc(Hb, Hb, S_A, DF, DF, DF, NS, NS / 128, NS / 128, 0, 0.03125f);
    mgemm<<<s0.nBlocks, 256, 0, stream>>>(s0, z, z);
    SmDesc m0 = {S_A, L, nullptr};
    dsoftmax3<<<NS, 256, 0, stream>>>(m0, zs, zs, NS);

    GemmDesc a0 = mkdesc(S_A, HbT, Hc0, NS, NS, NS, DF, DF / 128, NS / 128, 0, 1.0f);
    GemmDesc s1 = mkdesc(Hb, Hlb, S_B, DF, DF, DF, NS, NS / 128, NS / 128, 0, 0.03125f);
    mgemm<<<a0.nBlocks + s1.nBlocks, 256, 0, stream>>>(a0, s1, z);
    SmDesc m1 = {S_B, nullptr, mlT};
    dsoftmax3<<<NS, 256, 0, stream>>>(m1, zs, zs, NS);

    GemmDesc a1 = mkdesc(S_B, HlbT, Hc1, NS, NS, NS, DF, DF / 128, NS / 128, 0, 1.0f);
    GemmDesc s2 = mkdesc(Hb, Hhb, S_A, DF, DF, DF, NS, NS / 128, NS / 128, 0, 0.03125f);
    mgemm<<<a1.nBlocks + s2.nBlocks, 256, 0, stream>>>(a1, s2, z);
    SmDesc m2 = {S_A, B_high, nullptr};
    dsoftmax3<<<NS, 256, 0, stream>>>(m2, zs, zs, NS);

    GemmDesc a2 = mkdesc(S_A, HhbT, Hc2, NS, NS, NS, DF, DF / 128, NS / 128, 0, 1.0f);
    GemmDesc w0 = mkdesc(Hc0, Wb,      P0, DF, DF, 3 * DF, DF, DF / 128, NS / 128, 1, 1.0f);
    GemmDesc w1 = mkdesc(Hc1, Wb + DF, P1, DF, DF, 3 * DF, DF, DF / 128, NS / 128, 1, 1.0f);
    mgemm<<<a2.nBlocks + w0.nBlocks + w1.nBlocks, 256, 0, stream>>>(a2, w0, w1);

    GemmDesc w2 = mkdesc(Hc2, Wb + 2 * DF, out, DF, DF, 3 * DF, DF, DF / 128, NS / 128, 2, 1.0f,
                         P0, P1, bvec);
    mgemm<<<w2.nBlocks, 256, 0, stream>>>(w2, z, z);
}

// Round 4
// 673.876 us; speedup vs baseline: 1.1446x; 1.0236x over previous
//
#include <hip/hip_runtime.h>

// ---------------------------------------------------------------------------
// SimplicialAttentionLayer2 on MI355X (gfx950)
// N=4096, D=1024.  3x: S=(H@KV^T)/32 -> softmax -> *mask -> softmax -> @KV
// out = tanh(concat(H1,H2,H3) @ W^T + b)
// R4: per-desc block ordering. A@KV and W launches use COLUMN-major bid
// ordering so XCD = bid%8 = bm%8 partitions the large A operand (S: 96 MB)
// across XCD L2s instead of replicating it 8x (R3: FETCH 406 MB vs 120 MB
// unique). S stored as 3 separate [4096,4096] bf16 matrices (lda=4096).
// ---------------------------------------------------------------------------

typedef unsigned short u16;
typedef unsigned int u32;
typedef __attribute__((ext_vector_type(8))) short short8;
typedef __attribute__((ext_vector_type(4))) float floatx4;

#define NS 4096
#define DF 1024

__device__ __forceinline__ u16 f2b(float x) {          // fp32 -> bf16 RNE
    u32 u = __float_as_uint(x);
    u32 r = (u + 0x7fffu + ((u >> 16) & 1u)) >> 16;
    return (u16)r;
}
__device__ __forceinline__ u32 packb(float a, float b) {
    return (u32)f2b(a) | ((u32)f2b(b) << 16);
}
__device__ __forceinline__ void unpack8(uint4 u, float* v) {
    v[0] = __uint_as_float(u.x << 16); v[1] = __uint_as_float(u.x & 0xffff0000u);
    v[2] = __uint_as_float(u.y << 16); v[3] = __uint_as_float(u.y & 0xffff0000u);
    v[4] = __uint_as_float(u.z << 16); v[5] = __uint_as_float(u.z & 0xffff0000u);
    v[6] = __uint_as_float(u.w << 16); v[7] = __uint_as_float(u.w & 0xffff0000u);
}

// ---------------------------------------------------------------------------
// Multi-GEMM: up to 3 independent NT sub-GEMMs per launch, routed by blockIdx.
// C[M,N] = epi(alpha * A[M,K] @ B[N,K]^T)
//   epi 0: bf16 store (alpha applied)
//   epi 1: fp32 store raw acc
//   epi 2: fp32 store tanh(acc + P0[idx] + P1[idx] + bias[col])
// colMajor: bm = bid % nTilesY (XCD = bm%8 partitions A row-tiles per XCD).
// ---------------------------------------------------------------------------
struct GemmDesc {
    const u16* A; const u16* B; void* C;
    const float* P0; const float* P1; const float* bias;
    int K, lda, ldb, ldc, nTilesX, nTilesY, nBlocks, colMajor, epi;
    float alpha;
};

__device__ __forceinline__ void gemm_body(const GemmDesc& d, int bid)
{
    __shared__ u16 As[128 * 64];
    __shared__ u16 Bs[128 * 64];

    const int tid  = threadIdx.x;
    const int wave = tid >> 6;
    const int lane = tid & 63;
    int bm, bn;
    if (d.colMajor) { bm = bid % d.nTilesY; bn = bid / d.nTilesY; }
    else            { bn = bid % d.nTilesX; bm = bid / d.nTilesX; }
    const int wm = wave >> 1, wn = wave & 1;
    const int q = lane >> 4, r16 = lane & 15;

    floatx4 acc[4][4];
#pragma unroll
    for (int i = 0; i < 4; i++)
#pragma unroll
        for (int j = 0; j < 4; j++) acc[i][j] = (floatx4){0.f, 0.f, 0.f, 0.f};

    const u16* Abase = d.A + (size_t)bm * 128 * d.lda;
    const u16* Bbase = d.B + (size_t)bn * 128 * d.ldb;
    const int lda = d.lda, ldb = d.ldb, K = d.K;

    for (int kt = 0; kt < K; kt += 64) {
        // stage tiles: LDS phys chunk c' at row holds logical chunk c'^(row&7)
#pragma unroll
        for (int i = 0; i < 4; i++) {
            int chunk = i * 256 + wave * 64 + lane;     // 16B chunk id
            int row   = chunk >> 3;                     // 8 chunks per 128B row
            int clog  = (chunk & 7) ^ (row & 7);
            const u16* ga = Abase + (size_t)row * lda + kt + clog * 8;
            const u16* gb = Bbase + (size_t)row * ldb + kt + clog * 8;
            __builtin_amdgcn_global_load_lds(
                (const __attribute__((address_space(1))) void*)ga,
                (__attribute__((address_space(3))) void*)&As[(i * 256 + wave * 64) * 8],
                16, 0, 0);
            __builtin_amdgcn_global_load_lds(
                (const __attribute__((address_space(1))) void*)gb,
                (__attribute__((address_space(3))) void*)&Bs[(i * 256 + wave * 64) * 8],
                16, 0, 0);
        }
        __syncthreads();

#pragma unroll
        for (int kk = 0; kk < 2; kk++) {
            short8 af[4], bfv[4];
#pragma unroll
            for (int mi = 0; mi < 4; mi++) {
                int row  = wm * 64 + mi * 16 + r16;     // A: m = lane&15
                int phys = (kk * 4 + q) ^ (row & 7);
                af[mi] = *(const short8*)&As[row * 64 + phys * 8];
            }
#pragma unroll
            for (int ni = 0; ni < 4; ni++) {
                int row  = wn * 64 + ni * 16 + r16;     // B: n = lane&15
                int phys = (kk * 4 + q) ^ (row & 7);
                bfv[ni] = *(const short8*)&Bs[row * 64 + phys * 8];
            }
#pragma unroll
            for (int mi = 0; mi < 4; mi++)
#pragma unroll
                for (int ni = 0; ni < 4; ni++)
                    acc[mi][ni] = __builtin_amdgcn_mfma_f32_16x16x32_bf16(
                        af[mi], bfv[ni], acc[mi][ni], 0, 0, 0);
        }
        __syncthreads();
    }

    // epilogue: D element (row = q*4 + r, col = lane&15)
#pragma unroll
    for (int mi = 0; mi < 4; mi++) {
#pragma unroll
        for (int ni = 0; ni < 4; ni++) {
            floatx4 v = acc[mi][ni];
            int col  = bn * 128 + wn * 64 + ni * 16 + r16;
            int rowb = bm * 128 + wm * 64 + mi * 16 + q * 4;
            if (d.epi == 0) {
                u16* C = (u16*)d.C;
#pragma unroll
                for (int r = 0; r < 4; r++)
                    C[(size_t)(rowb + r) * d.ldc + col] = f2b(v[r] * d.alpha);
            } else if (d.epi == 1) {
                float* C = (float*)d.C;
#pragma unroll
                for (int r = 0; r < 4; r++)
                    C[(size_t)(rowb + r) * d.ldc + col] = v[r];
            } else {
                float* C = (float*)d.C;
                float bb = d.bias[col];
#pragma unroll
                for (int r = 0; r < 4; r++) {
                    size_t idx = (size_t)(rowb + r) * d.ldc + col;
                    C[idx] = tanhf(v[r] + d.P0[idx] + d.P1[idx] + bb);
                }
            }
        }
    }
}

__global__ __launch_bounds__(256)
void mgemm(GemmDesc d0, GemmDesc d1, GemmDesc d2)
{
    int bid = blockIdx.x;
    if (bid < d0.nBlocks)                 { gemm_body(d0, bid); return; }
    bid -= d0.nBlocks;
    if (bid < d1.nBlocks)                 { gemm_body(d1, bid); return; }
    bid -= d1.nBlocks;
    gemm_body(d2, bid);
}

// ---------------------------------------------------------------------------
// Double softmax, branch-routed: grid = nbr*4096 blocks; branch = bid>>12.
// Row = 4096 bf16 at stride ldS, in-place. Mask: fp32 mF (!=0) or bit mask mB.
// ---------------------------------------------------------------------------
struct SmDesc { u16* S; const float* mF; const u32* mB; };

__device__ __forceinline__ float blockMax(float x, volatile float* red) {
#pragma unroll
    for (int off = 32; off > 0; off >>= 1) x = fmaxf(x, __shfl_xor(x, off, 64));
    __syncthreads();
    if ((threadIdx.x & 63) == 0) red[threadIdx.x >> 6] = x;
    __syncthreads();
    return fmaxf(fmaxf(red[0], red[1]), fmaxf(red[2], red[3]));
}
__device__ __forceinline__ float blockSum(float x, volatile float* red) {
#pragma unroll
    for (int off = 32; off > 0; off >>= 1) x += __shfl_xor(x, off, 64);
    __syncthreads();
    if ((threadIdx.x & 63) == 0) red[threadIdx.x >> 6] = x;
    __syncthreads();
    return red[0] + red[1] + red[2] + red[3];
}

__global__ __launch_bounds__(256)
void dsoftmax3(SmDesc d0, SmDesc d1, SmDesc d2, int ldS)
{
    __shared__ float red[4];
    const int bid = blockIdx.x;
    const int br  = bid >> 12;
    const int row = bid & 4095;
    const SmDesc d = (br == 0) ? d0 : (br == 1) ? d1 : d2;
    u16* Srow = d.S + (size_t)row * ldS;
    const int t = threadIdx.x;

    float v[16];
    uint4 u0 = ((const uint4*)Srow)[t * 2];
    uint4 u1 = ((const uint4*)Srow)[t * 2 + 1];
    unpack8(u0, v); unpack8(u1, v + 8);

    float m = -1e30f;
#pragma unroll
    for (int j = 0; j < 16; j++) m = fmaxf(m, v[j]);
    m = blockMax(m, red);

    float s = 0.f;
#pragma unroll
    for (int j = 0; j < 16; j++) { v[j] = __expf(v[j] - m); s += v[j]; }
    s = blockSum(s, red);
    float rz = 1.0f / s;

    float v2[16];
    if (d.mF) {
        const float* mrow = d.mF + (size_t)row * NS;
#pragma unroll
        for (int k = 0; k < 4; k++) {
            float4 mv = ((const float4*)mrow)[t * 4 + k];
            v2[k * 4 + 0] = (mv.x != 0.f) ? v[k * 4 + 0] * rz : 0.f;
            v2[k * 4 + 1] = (mv.y != 0.f) ? v[k * 4 + 1] * rz : 0.f;
            v2[k * 4 + 2] = (mv.z != 0.f) ? v[k * 4 + 2] * rz : 0.f;
            v2[k * 4 + 3] = (mv.w != 0.f) ? v[k * 4 + 3] * rz : 0.f;
        }
    } else {
        u32 w = d.mB[(size_t)row * (NS / 32) + (t >> 1)];
        u32 half = (w >> ((t & 1) * 16)) & 0xffffu;
#pragma unroll
        for (int j = 0; j < 16; j++)
            v2[j] = ((half >> j) & 1u) ? v[j] * rz : 0.f;
    }

    // second softmax: masked entries are logit 0 (still contribute exp)
    float m2 = -1e30f;
#pragma unroll
    for (int j = 0; j < 16; j++) m2 = fmaxf(m2, v2[j]);
    m2 = blockMax(m2, red);
    float s2 = 0.f;
#pragma unroll
    for (int j = 0; j < 16; j++) { v2[j] = __expf(v2[j] - m2); s2 += v2[j]; }
    s2 = blockSum(s2, red);
    float rz2 = 1.0f / s2;

    uint4 o0, o1;
    o0.x = packb(v2[0] * rz2,  v2[1] * rz2);
    o0.y = packb(v2[2] * rz2,  v2[3] * rz2);
    o0.z = packb(v2[4] * rz2,  v2[5] * rz2);
    o0.w = packb(v2[6] * rz2,  v2[7] * rz2);
    o1.x = packb(v2[8] * rz2,  v2[9] * rz2);
    o1.y = packb(v2[10] * rz2, v2[11] * rz2);
    o1.z = packb(v2[12] * rz2, v2[13] * rz2);
    o1.w = packb(v2[14] * rz2, v2[15] * rz2);
    ((uint4*)Srow)[t * 2]     = o0;
    ((uint4*)Srow)[t * 2 + 1] = o1;
}

// ---------------------------------------------------------------------------
// fp32 [NS,DF] -> bf16 [NS,DF] and bf16 transposed [DF,NS]; 3 inputs via z.
// ---------------------------------------------------------------------------
__global__ __launch_bounds__(256)
void cvt3(const float* __restrict__ X0, const float* __restrict__ X1,
          const float* __restrict__ X2, u16* __restrict__ Xball,
          u16* __restrict__ XbTall)
{
    __shared__ float tile[32][33];
    const float* X = (blockIdx.z == 0) ? X0 : (blockIdx.z == 1) ? X1 : X2;
    u16* Xb  = Xball  + (size_t)blockIdx.z * NS * DF;
    u16* XbT = XbTall + (size_t)blockIdx.z * NS * DF;
    const int tx = threadIdx.x, ty = threadIdx.y;
    const int bx = blockIdx.x * 32, by = blockIdx.y * 32;
#pragma unroll
    for (int k = 0; k < 4; k++) {
        int r = by + ty + k * 8;
        float val = X[(size_t)r * DF + bx + tx];
        tile[ty + k * 8][tx] = val;
        Xb[(size_t)r * DF + bx + tx] = f2b(val);
    }
    __syncthreads();
#pragma unroll
    for (int k = 0; k < 4; k++) {
        int c = bx + ty + k * 8;
        XbT[(size_t)c * NS + by + tx] = f2b(tile[tx][ty + k * 8]);
    }
}

// bit-packed transposed nonzero mask: MT[c*(n/32)+w] bit b = (X[w*32+b][c]!=0)
__global__ __launch_bounds__(256)
void mask_bits(const float* __restrict__ X, u32* __restrict__ MT, int n)
{
    __shared__ float tile[32][33];
    const int tx = threadIdx.x, ty = threadIdx.y;
    const int bx = blockIdx.x * 32, by = blockIdx.y * 32;
#pragma unroll
    for (int k = 0; k < 4; k++) {
        int r = by + ty + k * 8;
        tile[ty + k * 8][tx] = X[(size_t)r * n + bx + tx];
    }
    __syncthreads();
#pragma unroll
    for (int k = 0; k < 4; k++) {
        int c = bx + ty + k * 8;
        unsigned long long m = __ballot(tile[tx][ty + k * 8] != 0.f);
        u32 w = (ty & 1) ? (u32)(m >> 32) : (u32)m;
        if (tx == 0) MT[(size_t)c * (n / 32) + (by >> 5)] = w;
    }
}

__global__ __launch_bounds__(256)
void cvtk(const float* __restrict__ X, u16* __restrict__ Y, int n4)
{
    int i = blockIdx.x * 256 + threadIdx.x;
    if (i >= n4) return;
    float4 x = ((const float4*)X)[i];
    ushort4 y;
    y.x = f2b(x.x); y.y = f2b(x.y); y.z = f2b(x.z); y.w = f2b(x.w);
    ((ushort4*)Y)[i] = y;
}

// out = tanh(P0 + P1 + P2 + bias[col]); 4096x1024 fp32, float4 per thread.
__global__ __launch_bounds__(256)
void combine(const float* __restrict__ P0, const float* __restrict__ P1,
             const float* __restrict__ P2, const float* __restrict__ bias,
             float* __restrict__ out)
{
    int i = blockIdx.x * 256 + threadIdx.x;       // float4 index
    float4 a = ((const float4*)P0)[i];
    float4 b = ((const float4*)P1)[i];
    float4 c = ((const float4*)P2)[i];
    float4 bb = ((const float4*)bias)[i & 255];   // 1024 cols = 256 float4
    float4 o;
    o.x = tanhf(a.x + b.x + c.x + bb.x);
    o.y = tanhf(a.y + b.y + c.y + bb.y);
    o.z = tanhf(a.z + b.z + c.z + bb.z);
    o.w = tanhf(a.w + b.w + c.w + bb.w);
    ((float4*)out)[i] = o;
}

// ---------------------------------------------------------------------------
static inline GemmDesc mkdesc(const u16* A, const u16* B, void* C,
                              int K, int lda, int ldb, int ldc,
                              int nTilesX, int nTilesY, int epi, float alpha,
                              int colMajor = 0,
                              const float* P0 = nullptr, const float* P1 = nullptr,
                              const float* bias = nullptr)
{
    GemmDesc d;
    d.A = A; d.B = B; d.C = C; d.P0 = P0; d.P1 = P1; d.bias = bias;
    d.K = K; d.lda = lda; d.ldb = ldb; d.ldc = ldc;
    d.nTilesX = nTilesX; d.nTilesY = nTilesY; d.nBlocks = nTilesX * nTilesY;
    d.colMajor = colMajor; d.epi = epi; d.alpha = alpha;
    return d;
}

extern "C" void kernel_launch(void* const* d_in, const int* in_sizes, int n_in,
                              void* d_out, int out_size, void* d_ws, size_t ws_size,
                              hipStream_t stream)
{
    const float* L      = (const float*)d_in[0];
    const float* H      = (const float*)d_in[1];
    const float* B_low  = (const float*)d_in[2];
    const float* H_low  = (const float*)d_in[3];
    const float* B_high = (const float*)d_in[4];
    const float* H_high = (const float*)d_in[5];
    const float* W      = (const float*)d_in[6];
    const float* bvec   = (const float*)d_in[7];
    float* out = (float*)d_out;

    const size_t MB = 1024 * 1024;
    char* ws = (char*)d_ws;
    GemmDesc z = {};
    dim3 bt(32, 8);

    // ---- fused uniform-work schedule (176 MB) ----
    u16* S0    = (u16*)(ws + 0);            // 32 MB [4096,4096] bf16
    u16* S1    = (u16*)(ws + 32 * MB);      // 32 MB
    u16* S2    = (u16*)(ws + 64 * MB);      // 32 MB
    float* P0  = (float*)(ws + 0);          //   16 MB (S dead by then)
    float* P1  = (float*)(ws + 16 * MB);
    float* P2  = (float*)(ws + 32 * MB);
    u16* Hcat  = (u16*)(ws + 96 * MB);      // 24 MB [12288,1024] bf16
    u16* HTcat = (u16*)(ws + 120 * MB);     // 24 MB 3x [1024,4096] bf16
    u16* Hc    = (u16*)(ws + 144 * MB);     // 24 MB [4096,3072] bf16
    u16* Wb    = (u16*)(ws + 168 * MB);     // 6 MB
    u32* mlT   = (u32*)(ws + 174 * MB);     // 2 MB

    cvt3<<<dim3(DF / 32, NS / 32, 3), bt, 0, stream>>>(H, H_low, H_high, Hcat, HTcat);
    cvtk<<<(DF * 3 * DF / 4 + 255) / 256, 256, 0, stream>>>(W, Wb, DF * 3 * DF / 4);
    mask_bits<<<dim3(NS / 32, NS / 32), bt, 0, stream>>>(B_low, mlT, NS);

    // S_b = (H @ KV_b^T)/32   [3 x 1024 uniform blocks; operands symmetric]
    GemmDesc sg0 = mkdesc(Hcat, Hcat,               S0, DF, DF, DF, NS, NS / 128, NS / 128, 0, 0.03125f);
    GemmDesc sg1 = mkdesc(Hcat, Hcat + NS * DF,     S1, DF, DF, DF, NS, NS / 128, NS / 128, 0, 0.03125f);
    GemmDesc sg2 = mkdesc(Hcat, Hcat + 2 * NS * DF, S2, DF, DF, DF, NS, NS / 128, NS / 128, 0, 0.03125f);
    mgemm<<<3 * 1024, 256, 0, stream>>>(sg0, sg1, sg2);

    // fused double softmax over 12288 rows
    SmDesc s0 = {S0, L,       nullptr};
    SmDesc s1 = {S1, nullptr, mlT};
    SmDesc s2 = {S2, B_high,  nullptr};
    dsoftmax3<<<3 * NS, 256, 0, stream>>>(s0, s1, s2, NS);

    // Hc[:, b*1024..] = A_b @ KV_b  [768 uniform K=4096 blocks, COL-major:
    // XCD = bm%8 partitions the 32 MB A operand per XCD]
    GemmDesc a0 = mkdesc(S0, HTcat,               Hc,          NS, NS, NS, 3 * DF, DF / 128, NS / 128, 0, 1.0f, 1);
    GemmDesc a1 = mkdesc(S1, HTcat + NS * DF,     Hc + DF,     NS, NS, NS, 3 * DF, DF / 128, NS / 128, 0, 1.0f, 1);
    GemmDesc a2 = mkdesc(S2, HTcat + 2 * NS * DF, Hc + 2 * DF, NS, NS, NS, 3 * DF, DF / 128, NS / 128, 0, 1.0f, 1);
    mgemm<<<a0.nBlocks + a1.nBlocks + a2.nBlocks, 256, 0, stream>>>(a0, a1, a2);

    // P_b = Hc_b @ W_b^T (fp32 partials)  [768 uniform K=1024 blocks, COL-major]
    GemmDesc w0 = mkdesc(Hc,          Wb,          P0, DF, 3 * DF, 3 * DF, DF, DF / 128, NS / 128, 1, 1.0f, 1);
    GemmDesc w1 = mkdesc(Hc + DF,     Wb + DF,     P1, DF, 3 * DF, 3 * DF, DF, DF / 128, NS / 128, 1, 1.0f, 1);
    GemmDesc w2 = mkdesc(Hc + 2 * DF, Wb + 2 * DF, P2, DF, 3 * DF, 3 * DF, DF, DF / 128, NS / 128, 1, 1.0f, 1);
    mgemm<<<w0.nBlocks + w1.nBlocks + w2.nBlocks, 256, 0, stream>>>(w0, w1, w2);

    // out = tanh(P0+P1+P2+b)
    combine<<<NS * DF / 4 / 256, 256, 0, stream>>>(P0, P1, P2, bvec, out);
}